// Round 4
// baseline (1739.174 us; speedup 1.0000x reference)
//
#include <hip/hip_runtime.h>
#include <hip/hip_bf16.h>

#define N_NODES 20000
#define N_EDGES 320000
#define F_IN    128
#define F_HID   32
#define NHEAD   8
#define FDIM    256   // NHEAD * D for both layers
#define CAP     96    // max in-degree capacity; P(Poisson(16) > 96) ~ 1e-44

typedef __hip_bfloat16 bf16;

// ---------------- bucket build (replaces hist+scan+fill CSR) ----------------
__global__ void zero_kernel(int* __restrict__ p, int n){
  int i = blockIdx.x*256 + threadIdx.x;
  if (i < n) p[i] = 0;
}

__global__ void fill_bucket_kernel(const int* __restrict__ src, const int* __restrict__ dst,
                                   int* __restrict__ cnt, int* __restrict__ bucket, int e){
  int i = blockIdx.x*256 + threadIdx.x;
  if (i < e){
    int d = dst[i];
    int p = atomicAdd(&cnt[d], 1);
    if (p < CAP) bucket[(size_t)d*CAP + p] = src[i];
  }
}

// ---------------- feat = x @ W ; el/er = head-dot with al/ar ----------------
// block = 256 threads (thread = output column), NODES nodes per block.
// W prefetched in 8-row chunks into registers; x tile in LDS (broadcast reads).
template<int K, int NODES>
__global__ __launch_bounds__(256) void gemm_aux_kernel(
    const float* __restrict__ x, const float* __restrict__ W,
    const float* __restrict__ al, const float* __restrict__ ar,
    bf16* __restrict__ feat, float* __restrict__ el, float* __restrict__ er)
{
  const int tid = threadIdx.x;
  const int n0  = blockIdx.x * NODES;
  __shared__ float xl[NODES * K];
  #pragma unroll
  for (int i = tid; i < (NODES*K)/4; i += 256)
    ((float4*)xl)[i] = ((const float4*)(x + (size_t)n0*K))[i];
  __syncthreads();

  float acc[NODES];
  #pragma unroll
  for (int nn = 0; nn < NODES; nn++) acc[nn] = 0.f;

  float wr[8];
  #pragma unroll
  for (int j = 0; j < 8; j++) wr[j] = W[j*FDIM + tid];

  #pragma unroll
  for (int kk = 0; kk < K; kk += 8){
    float wn[8];
    if (kk + 8 < K){
      #pragma unroll
      for (int j = 0; j < 8; j++) wn[j] = W[(kk+8+j)*FDIM + tid];  // prefetch next chunk
    }
    #pragma unroll
    for (int nn = 0; nn < NODES; nn++){
      float4 xa = *(const float4*)&xl[nn*K + kk];     // wave-uniform broadcast
      float4 xb = *(const float4*)&xl[nn*K + kk + 4];
      acc[nn] = fmaf(xa.x, wr[0], acc[nn]);
      acc[nn] = fmaf(xa.y, wr[1], acc[nn]);
      acc[nn] = fmaf(xa.z, wr[2], acc[nn]);
      acc[nn] = fmaf(xa.w, wr[3], acc[nn]);
      acc[nn] = fmaf(xb.x, wr[4], acc[nn]);
      acc[nn] = fmaf(xb.y, wr[5], acc[nn]);
      acc[nn] = fmaf(xb.z, wr[6], acc[nn]);
      acc[nn] = fmaf(xb.w, wr[7], acc[nn]);
    }
    if (kk + 8 < K){
      #pragma unroll
      for (int j = 0; j < 8; j++) wr[j] = wn[j];
    }
  }

  const float alv = al[tid];
  const float arv = ar[tid];
  #pragma unroll
  for (int nn = 0; nn < NODES; nn++){
    const int nidx = n0 + nn;
    feat[(size_t)nidx*FDIM + tid] = __float2bfloat16(acc[nn]);
    float e_l = acc[nn] * alv;
    float e_r = acc[nn] * arv;
    #pragma unroll
    for (int off = 16; off >= 1; off >>= 1){
      e_l += __shfl_xor(e_l, off);   // stays within the 32-lane head group
      e_r += __shfl_xor(e_r, off);
    }
    if ((tid & 31) == 0){
      el[nidx*NHEAD + (tid >> 5)] = e_l;
      er[nidx*NHEAD + (tid >> 5)] = e_r;
    }
  }
}

// ---------------- per-dst-node edge softmax + aggregate ----------------
// block = 256 threads = 4 waves. Phase A: logits+softmax weights in LDS.
// Phase B: each half-wave (32 lanes) loads one full feat row per dwordx4
// (lane l covers cols 8l..8l+7, single head h=l>>2); 2 edges per wave-inst.
template<int RELU_MEAN>
__global__ __launch_bounds__(256) void edge_agg_kernel(
    const bf16* __restrict__ feat, const float* __restrict__ el,
    const float* __restrict__ er, const int* __restrict__ cnt,
    const int* __restrict__ bucket, const float* __restrict__ bias,
    float* __restrict__ outp)
{
  const int n   = blockIdx.x;
  const int tid = threadIdx.x;
  __shared__ float t_lds[128*9];    // stride 9: conflict-free
  __shared__ int   srcs[128];
  __shared__ float er_lds[NHEAD];
  __shared__ float s_lds[NHEAD];
  __shared__ float red[4*256];      // per-wave partial columns
  __shared__ float red2[256];
  int C = cnt[n];
  if (C > CAP) C = CAP;
  if (tid < NHEAD) er_lds[tid] = er[n*NHEAD + tid];
  __syncthreads();

  // ---- Phase A: logits, per-head max, exp weights, denominator ----
  if (tid < C){
    const int sidx = bucket[(size_t)n*CAP + tid];
    srcs[tid] = sidx;
    const float4* e4 = (const float4*)(el + (size_t)sidx*NHEAD);
    float4 a = e4[0], bq = e4[1];
    float ev[8] = {a.x, a.y, a.z, a.w, bq.x, bq.y, bq.z, bq.w};
    #pragma unroll
    for (int hh = 0; hh < 8; hh++){
      float v = ev[hh] + er_lds[hh];
      t_lds[tid*9 + hh] = (v > 0.f) ? v : 0.2f*v;   // leaky_relu(0.2)
    }
  }
  __syncthreads();
  {
    const int h = tid >> 5, d = tid & 31;
    float lm = -INFINITY;
    for (int e = d; e < C; e += 32) lm = fmaxf(lm, t_lds[e*9 + h]);
    #pragma unroll
    for (int off = 16; off >= 1; off >>= 1) lm = fmaxf(lm, __shfl_xor(lm, off));
    float ls = 0.f;
    for (int e = d; e < C; e += 32){
      float ex = __expf(t_lds[e*9 + h] - lm);
      t_lds[e*9 + h] = ex;     // store weight in place
      ls += ex;
    }
    #pragma unroll
    for (int off = 16; off >= 1; off >>= 1) ls += __shfl_xor(ls, off);
    if (d == 0) s_lds[h] = ls;
  }
  __syncthreads();

  // ---- Phase B: weighted aggregation, 8 cols/lane via dwordx4 bf16 ----
  const int wv   = tid >> 6;
  const int lane = tid & 63;
  const int sub  = lane >> 5;       // which edge of the pair
  const int l    = lane & 31;       // 32 lanes cover 256 cols, 8 each
  const int hB   = l >> 2;          // head owning cols 8l..8l+7
  float acc[8] = {0,0,0,0,0,0,0,0};
  for (int e = wv*2 + sub; e < C; e += 8){
    const int sidx = srcs[e];
    const float4 fv = *(const float4*)(feat + (size_t)sidx*FDIM + (l << 3));
    const float w = t_lds[e*9 + hB];
    const unsigned* u = (const unsigned*)&fv;
    #pragma unroll
    for (int j = 0; j < 4; j++){
      float flo = __uint_as_float(u[j] << 16);           // col 8l+2j
      float fhi = __uint_as_float(u[j] & 0xFFFF0000u);   // col 8l+2j+1
      acc[2*j]   = fmaf(w, flo, acc[2*j]);
      acc[2*j+1] = fmaf(w, fhi, acc[2*j+1]);
    }
  }
  #pragma unroll
  for (int j = 0; j < 8; j++) acc[j] += __shfl_xor(acc[j], 32);  // fold edge-pair halves
  if (lane < 32){
    float4* r4 = (float4*)&red[wv*256 + l*8];
    r4[0] = make_float4(acc[0], acc[1], acc[2], acc[3]);
    r4[1] = make_float4(acc[4], acc[5], acc[6], acc[7]);
  }
  __syncthreads();

  // ---- epilogue: cross-wave sum, softmax divide, bias, head mean ----
  {
    float sum = red[tid] + red[256 + tid] + red[512 + tid] + red[768 + tid];
    float val = (C > 0) ? (sum / s_lds[tid >> 5]) : 0.f;
    val += bias[tid];
    if (RELU_MEAN) val = fmaxf(val, 0.f);
    red2[tid] = val;
  }
  __syncthreads();
  if (tid < 32){
    float sum = 0.f;
    #pragma unroll
    for (int hh = 0; hh < 8; hh++) sum += red2[hh*32 + tid];
    sum *= 0.125f;   // mean over heads
    outp[(size_t)n*32 + tid] = sum;
  }
}

extern "C" void kernel_launch(void* const* d_in, const int* in_sizes, int n_in,
                              void* d_out, int out_size, void* d_ws, size_t ws_size,
                              hipStream_t stream)
{
  const float* x   = (const float*)d_in[0];
  const int*   src = (const int*)  d_in[1];
  const int*   dst = (const int*)  d_in[2];
  const float* W1  = (const float*)d_in[3];
  const float* al1 = (const float*)d_in[4];
  const float* ar1 = (const float*)d_in[5];
  const float* b1  = (const float*)d_in[6];
  const float* W2  = (const float*)d_in[7];
  const float* al2 = (const float*)d_in[8];
  const float* ar2 = (const float*)d_in[9];
  const float* b2  = (const float*)d_in[10];
  (void)in_sizes; (void)n_in; (void)out_size; (void)ws_size;

  size_t o = 0;
  char* base = (char*)d_ws;
  auto take = [&](size_t bytes) -> char* {
    char* p = base + o;
    o += (bytes + 255) & ~(size_t)255;
    return p;
  };
  bf16*  feat   = (bf16*) take((size_t)N_NODES*FDIM*2);
  float* el     = (float*)take((size_t)N_NODES*NHEAD*4);
  float* er     = (float*)take((size_t)N_NODES*NHEAD*4);
  float* hbuf   = (float*)take((size_t)N_NODES*F_HID*4);
  int*   cnt    = (int*)  take((size_t)N_NODES*4);
  int*   bucket = (int*)  take((size_t)N_NODES*CAP*4);

  // bucket build (shared by both layers)
  zero_kernel<<<(N_NODES+255)/256, 256, 0, stream>>>(cnt, N_NODES);
  fill_bucket_kernel<<<(N_EDGES+255)/256, 256, 0, stream>>>(src, dst, cnt, bucket, N_EDGES);

  // layer 1
  gemm_aux_kernel<F_IN, 16><<<N_NODES/16, 256, 0, stream>>>(x, W1, al1, ar1, feat, el, er);
  edge_agg_kernel<1><<<N_NODES, 256, 0, stream>>>(feat, el, er, cnt, bucket, b1, hbuf);

  // layer 2
  gemm_aux_kernel<F_HID, 16><<<N_NODES/16, 256, 0, stream>>>(hbuf, W2, al2, ar2, feat, el, er);
  edge_agg_kernel<0><<<N_NODES, 256, 0, stream>>>(feat, el, er, cnt, bucket, b2, (float*)d_out);
}

// Round 5
// 243.079 us; speedup vs baseline: 7.1548x; 7.1548x over previous
//
#include <hip/hip_runtime.h>
#include <hip/hip_bf16.h>

#define N_NODES 20000
#define N_EDGES 320000
#define F_IN    128
#define F_HID   32
#define NHEAD   8
#define FDIM    256   // NHEAD * D for both layers
#define CAP     96    // max in-degree capacity; P(Poisson(16) > 96) ~ 1e-44

typedef __hip_bfloat16 bf16;

// ---------------- bucket build (replaces hist+scan+fill CSR) ----------------
__global__ void zero_kernel(int* __restrict__ p, int n){
  int i = blockIdx.x*256 + threadIdx.x;
  if (i < n) p[i] = 0;
}

__global__ void fill_bucket_kernel(const int* __restrict__ src, const int* __restrict__ dst,
                                   int* __restrict__ cnt, int* __restrict__ bucket, int e){
  int i = blockIdx.x*256 + threadIdx.x;
  if (i < e){
    int d = dst[i];
    int p = atomicAdd(&cnt[d], 1);
    if (p < CAP) bucket[(size_t)d*CAP + p] = src[i];
  }
}

// ---------------- feat = x @ W ; el/er = head-dot with al/ar ----------------
// block = 256 threads (thread = output column), NODES nodes per block.
// W prefetched in 8-row register chunks; kk loop kept ROLLED (#pragma unroll 1)
// — full unroll hoists all W loads and spills to scratch (round-4 lesson:
// VGPR 256, 3 GB spill traffic, 29x regression).
template<int K, int NODES>
__global__ __launch_bounds__(256, 4) void gemm_aux_kernel(
    const float* __restrict__ x, const float* __restrict__ W,
    const float* __restrict__ al, const float* __restrict__ ar,
    bf16* __restrict__ feat, float* __restrict__ el, float* __restrict__ er)
{
  const int tid = threadIdx.x;
  const int n0  = blockIdx.x * NODES;
  __shared__ float xl[NODES * K];
  #pragma unroll
  for (int i = tid; i < (NODES*K)/4; i += 256)
    ((float4*)xl)[i] = ((const float4*)(x + (size_t)n0*K))[i];
  __syncthreads();

  float acc[NODES];
  #pragma unroll
  for (int nn = 0; nn < NODES; nn++) acc[nn] = 0.f;

  float wr[8];
  #pragma unroll
  for (int j = 0; j < 8; j++) wr[j] = W[j*FDIM + tid];

  #pragma unroll 1
  for (int kk = 0; kk < K; kk += 8){
    float wn[8];
    const bool more = (kk + 8 < K);
    if (more){
      #pragma unroll
      for (int j = 0; j < 8; j++) wn[j] = W[(kk+8+j)*FDIM + tid];  // prefetch next chunk
    }
    #pragma unroll
    for (int nn = 0; nn < NODES; nn++){
      float4 xa = *(const float4*)&xl[nn*K + kk];     // wave-uniform broadcast
      float4 xb = *(const float4*)&xl[nn*K + kk + 4];
      acc[nn] = fmaf(xa.x, wr[0], acc[nn]);
      acc[nn] = fmaf(xa.y, wr[1], acc[nn]);
      acc[nn] = fmaf(xa.z, wr[2], acc[nn]);
      acc[nn] = fmaf(xa.w, wr[3], acc[nn]);
      acc[nn] = fmaf(xb.x, wr[4], acc[nn]);
      acc[nn] = fmaf(xb.y, wr[5], acc[nn]);
      acc[nn] = fmaf(xb.z, wr[6], acc[nn]);
      acc[nn] = fmaf(xb.w, wr[7], acc[nn]);
    }
    if (more){
      #pragma unroll
      for (int j = 0; j < 8; j++) wr[j] = wn[j];
    }
  }

  const float alv = al[tid];
  const float arv = ar[tid];
  #pragma unroll
  for (int nn = 0; nn < NODES; nn++){
    const int nidx = n0 + nn;
    feat[(size_t)nidx*FDIM + tid] = __float2bfloat16(acc[nn]);
    float e_l = acc[nn] * alv;
    float e_r = acc[nn] * arv;
    #pragma unroll
    for (int off = 16; off >= 1; off >>= 1){
      e_l += __shfl_xor(e_l, off);   // stays within the 32-lane head group
      e_r += __shfl_xor(e_r, off);
    }
    if ((tid & 31) == 0){
      el[nidx*NHEAD + (tid >> 5)] = e_l;
      er[nidx*NHEAD + (tid >> 5)] = e_r;
    }
  }
}

// ---------------- per-dst-node edge softmax + aggregate ----------------
// block = 256 threads = 4 waves. Phase A: logits+softmax weights in LDS.
// Phase B: each half-wave (32 lanes) loads one full feat row per dwordx4
// (lane l covers cols 8l..8l+7, single head h=l>>2); 2 edges per wave-inst.
template<int RELU_MEAN>
__global__ __launch_bounds__(256) void edge_agg_kernel(
    const bf16* __restrict__ feat, const float* __restrict__ el,
    const float* __restrict__ er, const int* __restrict__ cnt,
    const int* __restrict__ bucket, const float* __restrict__ bias,
    float* __restrict__ outp)
{
  const int n   = blockIdx.x;
  const int tid = threadIdx.x;
  __shared__ float t_lds[128*9];    // stride 9: conflict-free
  __shared__ int   srcs[128];
  __shared__ float er_lds[NHEAD];
  __shared__ float s_lds[NHEAD];
  __shared__ float red[4*256];      // per-wave partial columns
  __shared__ float red2[256];
  int C = cnt[n];
  if (C > CAP) C = CAP;
  if (tid < NHEAD) er_lds[tid] = er[n*NHEAD + tid];
  __syncthreads();

  // ---- Phase A: logits, per-head max, exp weights, denominator ----
  if (tid < C){
    const int sidx = bucket[(size_t)n*CAP + tid];
    srcs[tid] = sidx;
    const float4* e4 = (const float4*)(el + (size_t)sidx*NHEAD);
    float4 a = e4[0], bq = e4[1];
    float ev[8] = {a.x, a.y, a.z, a.w, bq.x, bq.y, bq.z, bq.w};
    #pragma unroll
    for (int hh = 0; hh < 8; hh++){
      float v = ev[hh] + er_lds[hh];
      t_lds[tid*9 + hh] = (v > 0.f) ? v : 0.2f*v;   // leaky_relu(0.2)
    }
  }
  __syncthreads();
  {
    const int h = tid >> 5, d = tid & 31;
    float lm = -INFINITY;
    for (int e = d; e < C; e += 32) lm = fmaxf(lm, t_lds[e*9 + h]);
    #pragma unroll
    for (int off = 16; off >= 1; off >>= 1) lm = fmaxf(lm, __shfl_xor(lm, off));
    float ls = 0.f;
    for (int e = d; e < C; e += 32){
      float ex = __expf(t_lds[e*9 + h] - lm);
      t_lds[e*9 + h] = ex;     // store weight in place
      ls += ex;
    }
    #pragma unroll
    for (int off = 16; off >= 1; off >>= 1) ls += __shfl_xor(ls, off);
    if (d == 0) s_lds[h] = ls;
  }
  __syncthreads();

  // ---- Phase B: weighted aggregation, 8 cols/lane via dwordx4 bf16 ----
  const int wv   = tid >> 6;
  const int lane = tid & 63;
  const int sub  = lane >> 5;       // which edge of the pair
  const int l    = lane & 31;       // 32 lanes cover 256 cols, 8 each
  const int hB   = l >> 2;          // head owning cols 8l..8l+7
  float acc[8] = {0,0,0,0,0,0,0,0};
  for (int e = wv*2 + sub; e < C; e += 8){
    const int sidx = srcs[e];
    const float4 fv = *(const float4*)(feat + (size_t)sidx*FDIM + (l << 3));
    const float w = t_lds[e*9 + hB];
    const unsigned* u = (const unsigned*)&fv;
    #pragma unroll
    for (int j = 0; j < 4; j++){
      float flo = __uint_as_float(u[j] << 16);           // col 8l+2j
      float fhi = __uint_as_float(u[j] & 0xFFFF0000u);   // col 8l+2j+1
      acc[2*j]   = fmaf(w, flo, acc[2*j]);
      acc[2*j+1] = fmaf(w, fhi, acc[2*j+1]);
    }
  }
  #pragma unroll
  for (int j = 0; j < 8; j++) acc[j] += __shfl_xor(acc[j], 32);  // fold edge-pair halves
  if (lane < 32){
    float4* r4 = (float4*)&red[wv*256 + l*8];
    r4[0] = make_float4(acc[0], acc[1], acc[2], acc[3]);
    r4[1] = make_float4(acc[4], acc[5], acc[6], acc[7]);
  }
  __syncthreads();

  // ---- epilogue: cross-wave sum, softmax divide, bias, head mean ----
  {
    float sum = red[tid] + red[256 + tid] + red[512 + tid] + red[768 + tid];
    float val = (C > 0) ? (sum / s_lds[tid >> 5]) : 0.f;
    val += bias[tid];
    if (RELU_MEAN) val = fmaxf(val, 0.f);
    red2[tid] = val;
  }
  __syncthreads();
  if (tid < 32){
    float sum = 0.f;
    #pragma unroll
    for (int hh = 0; hh < 8; hh++) sum += red2[hh*32 + tid];
    sum *= 0.125f;   // mean over heads
    outp[(size_t)n*32 + tid] = sum;
  }
}

extern "C" void kernel_launch(void* const* d_in, const int* in_sizes, int n_in,
                              void* d_out, int out_size, void* d_ws, size_t ws_size,
                              hipStream_t stream)
{
  const float* x   = (const float*)d_in[0];
  const int*   src = (const int*)  d_in[1];
  const int*   dst = (const int*)  d_in[2];
  const float* W1  = (const float*)d_in[3];
  const float* al1 = (const float*)d_in[4];
  const float* ar1 = (const float*)d_in[5];
  const float* b1  = (const float*)d_in[6];
  const float* W2  = (const float*)d_in[7];
  const float* al2 = (const float*)d_in[8];
  const float* ar2 = (const float*)d_in[9];
  const float* b2  = (const float*)d_in[10];
  (void)in_sizes; (void)n_in; (void)out_size; (void)ws_size;

  size_t o = 0;
  char* base = (char*)d_ws;
  auto take = [&](size_t bytes) -> char* {
    char* p = base + o;
    o += (bytes + 255) & ~(size_t)255;
    return p;
  };
  bf16*  feat   = (bf16*) take((size_t)N_NODES*FDIM*2);
  float* el     = (float*)take((size_t)N_NODES*NHEAD*4);
  float* er     = (float*)take((size_t)N_NODES*NHEAD*4);
  float* hbuf   = (float*)take((size_t)N_NODES*F_HID*4);
  int*   cnt    = (int*)  take((size_t)N_NODES*4);
  int*   bucket = (int*)  take((size_t)N_NODES*CAP*4);

  // bucket build (shared by both layers)
  zero_kernel<<<(N_NODES+255)/256, 256, 0, stream>>>(cnt, N_NODES);
  fill_bucket_kernel<<<(N_EDGES+255)/256, 256, 0, stream>>>(src, dst, cnt, bucket, N_EDGES);

  // layer 1
  gemm_aux_kernel<F_IN, 8><<<N_NODES/8, 256, 0, stream>>>(x, W1, al1, ar1, feat, el, er);
  edge_agg_kernel<1><<<N_NODES, 256, 0, stream>>>(feat, el, er, cnt, bucket, b1, hbuf);

  // layer 2
  gemm_aux_kernel<F_HID, 8><<<N_NODES/8, 256, 0, stream>>>(hbuf, W2, al2, ar2, feat, el, er);
  edge_agg_kernel<0><<<N_NODES, 256, 0, stream>>>(feat, el, er, cnt, bucket, b2, (float*)d_out);
}

// Round 6
// 213.527 us; speedup vs baseline: 8.1450x; 1.1384x over previous
//
#include <hip/hip_runtime.h>
#include <hip/hip_bf16.h>

#define N_NODES 20000
#define N_EDGES 320000
#define F_IN    128
#define F_HID   32
#define NHEAD   8
#define FDIM    256   // NHEAD * D for both layers
#define CAP     96    // max in-degree capacity; P(Poisson(16) > 96) ~ 1e-44

typedef __hip_bfloat16 bf16;

// ---------------- bucket build ----------------
__global__ void zero_kernel(int* __restrict__ p, int n){
  int i = blockIdx.x*256 + threadIdx.x;
  if (i < n) p[i] = 0;
}

__global__ void fill_bucket_kernel(const int* __restrict__ src, const int* __restrict__ dst,
                                   int* __restrict__ cnt, int* __restrict__ bucket, int e){
  int i = blockIdx.x*256 + threadIdx.x;
  if (i < e){
    int d = dst[i];
    int p = atomicAdd(&cnt[d], 1);
    if (p < CAP) bucket[(size_t)d*CAP + p] = src[i];
  }
}

// ---------------- feat = x @ W ; el/er = head-dot with al/ar ----------------
// block = 256 threads (thread = output column), 16 nodes per block (8:1
// FMA:ds_read ratio). kk loop ROLLED (#pragma unroll 1) — full unroll hoists
// all W loads and spills (round-4: VGPR 256, 3 GB scratch, 29x regression).
template<int K, int NODES>
__global__ __launch_bounds__(256) void gemm_aux_kernel(
    const float* __restrict__ x, const float* __restrict__ W,
    const float* __restrict__ al, const float* __restrict__ ar,
    bf16* __restrict__ feat, float* __restrict__ el, float* __restrict__ er)
{
  const int tid = threadIdx.x;
  const int n0  = blockIdx.x * NODES;
  __shared__ float xl[NODES * K];

  // issue W chunk-0 loads first so their latency overlaps the staging barrier
  float wr[8];
  #pragma unroll
  for (int j = 0; j < 8; j++) wr[j] = W[j*FDIM + tid];

  #pragma unroll
  for (int i = tid; i < (NODES*K)/4; i += 256)
    ((float4*)xl)[i] = ((const float4*)(x + (size_t)n0*K))[i];
  __syncthreads();

  float acc[NODES];
  #pragma unroll
  for (int nn = 0; nn < NODES; nn++) acc[nn] = 0.f;

  #pragma unroll 1
  for (int kk = 0; kk < K; kk += 8){
    float wn[8];
    const bool more = (kk + 8 < K);
    if (more){
      #pragma unroll
      for (int j = 0; j < 8; j++) wn[j] = W[(kk+8+j)*FDIM + tid];  // prefetch next chunk
    }
    #pragma unroll
    for (int nn = 0; nn < NODES; nn++){
      float4 xa = *(const float4*)&xl[nn*K + kk];     // wave-uniform broadcast
      float4 xb = *(const float4*)&xl[nn*K + kk + 4];
      acc[nn] = fmaf(xa.x, wr[0], acc[nn]);
      acc[nn] = fmaf(xa.y, wr[1], acc[nn]);
      acc[nn] = fmaf(xa.z, wr[2], acc[nn]);
      acc[nn] = fmaf(xa.w, wr[3], acc[nn]);
      acc[nn] = fmaf(xb.x, wr[4], acc[nn]);
      acc[nn] = fmaf(xb.y, wr[5], acc[nn]);
      acc[nn] = fmaf(xb.z, wr[6], acc[nn]);
      acc[nn] = fmaf(xb.w, wr[7], acc[nn]);
    }
    if (more){
      #pragma unroll
      for (int j = 0; j < 8; j++) wr[j] = wn[j];
    }
  }

  const float alv = al[tid];
  const float arv = ar[tid];
  #pragma unroll
  for (int nn = 0; nn < NODES; nn++){
    const int nidx = n0 + nn;
    feat[(size_t)nidx*FDIM + tid] = __float2bfloat16(acc[nn]);
    float e_l = acc[nn] * alv;
    float e_r = acc[nn] * arv;
    #pragma unroll
    for (int off = 16; off >= 1; off >>= 1){
      e_l += __shfl_xor(e_l, off);   // stays within the 32-lane head group
      e_r += __shfl_xor(e_r, off);
    }
    if ((tid & 31) == 0){
      el[nidx*NHEAD + (tid >> 5)] = e_l;
      er[nidx*NHEAD + (tid >> 5)] = e_r;
    }
  }
}

// ---------------- per-dst-node edge softmax + aggregate ----------------
// WAVE-PER-NODE: 4 waves/block, each wave owns one node; all cross-lane
// traffic stays inside the wave (lockstep) -> ZERO __syncthreads, no
// cross-wave reduction. Per-wave LDS slices. Phase B: half-wave per edge,
// dwordx4 gathers (2 edges / wave-inst).
template<int RELU_MEAN>
__global__ __launch_bounds__(256) void edge_agg_kernel(
    const bf16* __restrict__ feat, const float* __restrict__ el,
    const float* __restrict__ er, const int* __restrict__ cnt,
    const int* __restrict__ bucket, const float* __restrict__ bias,
    float* __restrict__ outp)
{
  const int tid  = threadIdx.x;
  const int wv   = tid >> 6;
  const int lane = tid & 63;
  const int n    = blockIdx.x*4 + wv;

  __shared__ float t_all[4][CAP*9];   // stride 9: conflict-free
  __shared__ int   s_all[4][CAP];
  __shared__ float sum_all[4][NHEAD];
  __shared__ float v_all[4][256];
  float* t_w = t_all[wv];
  int*   s_w = s_all[wv];

  int C = cnt[n];
  if (C > CAP) C = CAP;

  // er row (uniform address, L1 broadcast)
  const float4* er4 = (const float4*)(er + (size_t)n*NHEAD);
  float4 era = er4[0], erb = er4[1];
  const float erv[8] = {era.x, era.y, era.z, era.w, erb.x, erb.y, erb.z, erb.w};

  // ---- Phase A: logits for this node's edges ----
  for (int e = lane; e < C; e += 64){
    const int sidx = bucket[(size_t)n*CAP + e];
    s_w[e] = sidx;
    const float4* e4 = (const float4*)(el + (size_t)sidx*NHEAD);
    float4 a = e4[0], bq = e4[1];
    float ev[8] = {a.x, a.y, a.z, a.w, bq.x, bq.y, bq.z, bq.w};
    #pragma unroll
    for (int hh = 0; hh < 8; hh++){
      float v = ev[hh] + erv[hh];
      t_w[e*9 + hh] = (v > 0.f) ? v : 0.2f*v;   // leaky_relu(0.2)
    }
  }
  // per-head max + exp + denominator: 8 lanes per head (h = lane>>3, d = lane&7)
  {
    const int h = lane >> 3, d = lane & 7;
    float lm = -INFINITY;
    for (int e = d; e < C; e += 8) lm = fmaxf(lm, t_w[e*9 + h]);
    #pragma unroll
    for (int off = 4; off >= 1; off >>= 1) lm = fmaxf(lm, __shfl_xor(lm, off));
    float ls = 0.f;
    for (int e = d; e < C; e += 8){
      float ex = __expf(t_w[e*9 + h] - lm);
      t_w[e*9 + h] = ex;       // weight stored in place (owner-writes)
      ls += ex;
    }
    #pragma unroll
    for (int off = 4; off >= 1; off >>= 1) ls += __shfl_xor(ls, off);
    if (d == 0) sum_all[wv][h] = ls;
  }

  // ---- Phase B: weighted aggregation, half-wave per edge, 8 cols/lane ----
  const int sub = lane >> 5;        // which edge of the pair
  const int l   = lane & 31;        // 32 lanes cover 256 cols, 8 each
  const int hB  = l >> 2;           // head owning cols 8l..8l+7
  float acc[8] = {0,0,0,0,0,0,0,0};
  for (int e = sub; e < C; e += 2){
    const int sidx = s_w[e];
    const float4 fv = *(const float4*)(feat + (size_t)sidx*FDIM + (l << 3));
    const float w = t_w[e*9 + hB];
    const unsigned* u = (const unsigned*)&fv;
    #pragma unroll
    for (int j = 0; j < 4; j++){
      float flo = __uint_as_float(u[j] << 16);           // col 8l+2j
      float fhi = __uint_as_float(u[j] & 0xFFFF0000u);   // col 8l+2j+1
      acc[2*j]   = fmaf(w, flo, acc[2*j]);
      acc[2*j+1] = fmaf(w, fhi, acc[2*j+1]);
    }
  }
  #pragma unroll
  for (int j = 0; j < 8; j++) acc[j] += __shfl_xor(acc[j], 32);  // fold edge pair

  // ---- epilogue (wave-local): divide, bias, relu, head-mean ----
  if (l == lane){ /* keep scopes tight */ }
  if (lane < 32){
    const float s = sum_all[wv][l >> 2];
    const float4* b4 = (const float4*)(bias + (l << 3));
    float4 ba = b4[0], bb = b4[1];
    float bv[8] = {ba.x, ba.y, ba.z, ba.w, bb.x, bb.y, bb.z, bb.w};
    float v[8];
    #pragma unroll
    for (int j = 0; j < 8; j++){
      float val = (C > 0) ? (acc[j] / s) : 0.f;
      val += bv[j];
      if (RELU_MEAN) val = fmaxf(val, 0.f);
      v[j] = val;
    }
    float4* v4 = (float4*)&v_all[wv][l << 3];
    v4[0] = make_float4(v[0], v[1], v[2], v[3]);
    v4[1] = make_float4(v[4], v[5], v[6], v[7]);
  }
  if (lane < 32){
    float sum = 0.f;
    #pragma unroll
    for (int hh = 0; hh < 8; hh++) sum += v_all[wv][hh*32 + lane];
    sum *= 0.125f;   // mean over heads
    outp[(size_t)n*32 + lane] = sum;
  }
}

extern "C" void kernel_launch(void* const* d_in, const int* in_sizes, int n_in,
                              void* d_out, int out_size, void* d_ws, size_t ws_size,
                              hipStream_t stream)
{
  const float* x   = (const float*)d_in[0];
  const int*   src = (const int*)  d_in[1];
  const int*   dst = (const int*)  d_in[2];
  const float* W1  = (const float*)d_in[3];
  const float* al1 = (const float*)d_in[4];
  const float* ar1 = (const float*)d_in[5];
  const float* b1  = (const float*)d_in[6];
  const float* W2  = (const float*)d_in[7];
  const float* al2 = (const float*)d_in[8];
  const float* ar2 = (const float*)d_in[9];
  const float* b2  = (const float*)d_in[10];
  (void)in_sizes; (void)n_in; (void)out_size; (void)ws_size;

  size_t o = 0;
  char* base = (char*)d_ws;
  auto take = [&](size_t bytes) -> char* {
    char* p = base + o;
    o += (bytes + 255) & ~(size_t)255;
    return p;
  };
  bf16*  feat   = (bf16*) take((size_t)N_NODES*FDIM*2);
  float* el     = (float*)take((size_t)N_NODES*NHEAD*4);
  float* er     = (float*)take((size_t)N_NODES*NHEAD*4);
  float* hbuf   = (float*)take((size_t)N_NODES*F_HID*4);
  int*   cnt    = (int*)  take((size_t)N_NODES*4);
  int*   bucket = (int*)  take((size_t)N_NODES*CAP*4);

  // bucket build (shared by both layers)
  zero_kernel<<<(N_NODES+255)/256, 256, 0, stream>>>(cnt, N_NODES);
  fill_bucket_kernel<<<(N_EDGES+255)/256, 256, 0, stream>>>(src, dst, cnt, bucket, N_EDGES);

  // layer 1
  gemm_aux_kernel<F_IN, 16><<<N_NODES/16, 256, 0, stream>>>(x, W1, al1, ar1, feat, el, er);
  edge_agg_kernel<1><<<N_NODES/4, 256, 0, stream>>>(feat, el, er, cnt, bucket, b1, hbuf);

  // layer 2
  gemm_aux_kernel<F_HID, 16><<<N_NODES/16, 256, 0, stream>>>(hbuf, W2, al2, ar2, feat, el, er);
  edge_agg_kernel<0><<<N_NODES/4, 256, 0, stream>>>(feat, el, er, cnt, bucket, b2, (float*)d_out);
}